// Round 1
// baseline (12136.250 us; speedup 1.0000x reference)
//
#include <hip/hip_runtime.h>

#define TSEQ 512
#define BATCH 64
#define DIN 1024
#define HID 512
#define G4 2048
#define CHK 64

typedef __attribute__((ext_vector_type(8))) short short8;
typedef __attribute__((ext_vector_type(4))) float floatx4;

__device__ __forceinline__ floatx4 mfma16(short8 a, short8 b, floatx4 c) {
  return __builtin_amdgcn_mfma_f32_16x16x32_bf16(a, b, c, 0, 0, 0);
}

__device__ __forceinline__ unsigned short f2bf(float f) {
  unsigned int u = __float_as_uint(f);
  unsigned int r = (u + 0x7fffu + ((u >> 16) & 1u)) >> 16;
  return (unsigned short)r;
}

__device__ __forceinline__ float sigm(float x) { return 1.f / (1.f + __expf(-x)); }
__device__ __forceinline__ float tanh_f(float x) {
  float xx = fminf(fmaxf(x, -15.f), 15.f);
  float e = __expf(2.f * xx);
  return (e - 1.f) / (e + 1.f);
}

// Convert fp32 x -> bf16 (same [T][B][DIN] layout, k-contiguous for B-fragments)
__global__ void k_convert_x(const float* __restrict__ x, unsigned short* __restrict__ xbf, int n4) {
  int i = blockIdx.x * 256 + threadIdx.x;
  if (i >= n4) return;
  floatx4 v = reinterpret_cast<const floatx4*>(x)[i];
  union { unsigned short us[4]; unsigned long long ull; } pk;
  pk.us[0] = f2bf(v[0]); pk.us[1] = f2bf(v[1]); pk.us[2] = f2bf(v[2]); pk.us[3] = f2bf(v[3]);
  reinterpret_cast<unsigned long long*>(xbf)[i] = pk.ull;
}

// Pre-arrange W [L][2][2048][K] fp32 into bf16 MFMA A-fragment order, with rows
// permuted so row' = 4*unit + gate  (orig row = gate*512 + unit).
__global__ void k_prep_w(const float* __restrict__ W, unsigned short* __restrict__ Wf, int K) {
  int mt = blockIdx.x, kt = blockIdx.y, ld = blockIdx.z;
  int lane = threadIdx.x;
  int rp = mt * 16 + (lane & 15);
  int row = (rp & 3) * HID + (rp >> 2);
  int k0 = kt * 32 + (lane >> 4) * 8;
  const float* src = W + (size_t)ld * G4 * K + (size_t)row * K + k0;
  unsigned short* dst = Wf + (size_t)ld * G4 * K + (((size_t)mt * (K / 32) + kt) * 64 + lane) * 8;
  for (int j = 0; j < 8; ++j) dst[j] = f2bf(src[j]);
}

// biasf[l][d][row'] = b_ih[l][d][orig] + b_hh[l][d][orig], permuted like W rows.
__global__ void k_prep_bias(const float* __restrict__ bih, const float* __restrict__ bhh,
                            float* __restrict__ biasf) {
  int i = blockIdx.x * 256 + threadIdx.x;  // 0 .. 4*2048-1
  int ld = i >> 11;
  int rp = i & 2047;
  int row = (rp & 3) * HID + (rp >> 2);
  biasf[i] = bih[ld * G4 + row] + bhh[ld * G4 + row];
}

// Zero the inter-block barrier counters (runs once per graph replay).
__global__ void k_zero_bar(unsigned int* bar) {
  if (threadIdx.x < 2) bar[threadIdx.x * 64] = 0;
}

// Input projection for one T-chunk (both directions). Unchanged from prev round.
__global__ __launch_bounds__(256, 2) void k_proj(
    const unsigned short* __restrict__ xin,   // [T][B][DIN] bf16
    const unsigned short* __restrict__ Wf,    // this layer: [2][G4*DIN] frag order
    const float* __restrict__ biasf,          // this layer: [2][G4] permuted
    float* __restrict__ pre,                  // [2][CHK][G4][B]
    int t0) {
  const int dir = blockIdx.z;
  const int w = threadIdx.x >> 6;
  const int lane = threadIdx.x & 63;
  const int quad = lane >> 4, col = lane & 15;
  const int tloc = blockIdx.y * 4 + w;
  const int tg = dir ? (TSEQ - 1 - (t0 + tloc)) : (t0 + tloc);
  const unsigned short* Wd = Wf + (size_t)dir * G4 * DIN;
  const unsigned short* xrow = xin + (size_t)tg * BATCH * DIN;

  floatx4 acc[8][4];
#pragma unroll
  for (int mi = 0; mi < 8; ++mi)
#pragma unroll
    for (int ni = 0; ni < 4; ++ni) acc[mi][ni] = (floatx4){0.f, 0.f, 0.f, 0.f};

#pragma unroll 4
  for (int kt = 0; kt < 32; ++kt) {
    short8 bfr[4];
#pragma unroll
    for (int ni = 0; ni < 4; ++ni) {
      int b = ni * 16 + col;
      bfr[ni] = *reinterpret_cast<const short8*>(xrow + (size_t)b * DIN + kt * 32 + quad * 8);
    }
#pragma unroll
    for (int mi = 0; mi < 8; ++mi) {
      size_t mt = (size_t)(blockIdx.x * 8 + mi);
      short8 afr = *reinterpret_cast<const short8*>(Wd + ((mt * 32 + kt) * 64 + lane) * 8);
#pragma unroll
      for (int ni = 0; ni < 4; ++ni) acc[mi][ni] = mfma16(afr, bfr[ni], acc[mi][ni]);
    }
  }

#pragma unroll
  for (int mi = 0; mi < 8; ++mi) {
    int gbase = blockIdx.x * 128 + mi * 16 + quad * 4;
#pragma unroll
    for (int r = 0; r < 4; ++r) {
      float bv = biasf[dir * G4 + gbase + r];
      float* prow = pre + (((size_t)dir * CHK + tloc) * G4 + gbase + r) * BATCH;
#pragma unroll
      for (int ni = 0; ni < 4; ++ni) prow[ni * 16 + col] = acc[mi][ni][r] + bv;
    }
  }
}

// Device-scope barrier across the 64 blocks of one direction.
// Monotonic target: no counter reset needed within a replay.
__device__ __forceinline__ void dir_barrier(unsigned int* ctr, unsigned int target) {
  __syncthreads();  // drains all waves' outstanding stores (vmcnt(0) before s_barrier)
  if (threadIdx.x == 0) {
    __threadfence();  // agent-scope release: publish our h slice across XCDs
    __hip_atomic_fetch_add(ctr, 1u, __ATOMIC_RELAXED, __HIP_MEMORY_SCOPE_AGENT);
    while (__hip_atomic_load(ctr, __ATOMIC_RELAXED, __HIP_MEMORY_SCOPE_AGENT) < target) {
      __builtin_amdgcn_s_sleep(1);
    }
    __threadfence();  // agent-scope acquire: invalidate stale L1/L2 before h reads
  }
  __syncthreads();
}

// Persistent recurrence kernel: runs CHK timesteps in ONE launch.
// Grid (64, 2) = 128 blocks <= 256 CUs -> all co-resident, spin-safe.
// Whh fragments held in registers for the whole launch; c-state in registers.
__global__ __launch_bounds__(256, 1) void k_steps(
    const unsigned short* __restrict__ Whhf,  // this layer: [2][G4*HID] frag order
    const float* __restrict__ pre,            // [2][CHK][G4][B]
    unsigned short* act1bf,                   // [T][B][DIN] bf16 (layer-1 h, layer-2 input)
    unsigned short* hT2,                      // [2 slots][2 dir][B][HID] bf16
    float* cst,                               // [2 layer][2 dir][HID][B] fp32
    float* __restrict__ dout,                 // [T][B][DIN] fp32
    unsigned int* bar,                        // [2 dirs] counters, 256B apart
    int t0, int layer, unsigned int bar_base) {
  const int dir = blockIdx.y;
  const int gb = blockIdx.x;
  const int w = threadIdx.x >> 6;
  const int lane = threadIdx.x & 63;
  const int quad = lane >> 4, col = lane & 15;
  const int b = w * 16 + col;
  unsigned int* ctr = bar + dir * 64;

  // Whh A-fragments for this block's 32 gate-rows: 32 x short8 = 128 VGPRs.
  const unsigned short* Wd = Whhf + (size_t)dir * G4 * HID;
  short8 wfr[16][2];
#pragma unroll
  for (int kt = 0; kt < 16; ++kt)
#pragma unroll
    for (int mi = 0; mi < 2; ++mi) {
      size_t mt = (size_t)(gb * 2 + mi);
      wfr[kt][mi] = *reinterpret_cast<const short8*>(Wd + ((mt * 16 + kt) * 64 + lane) * 8);
    }

  // c-state in registers across the whole chunk.
  float* cl = cst + ((size_t)layer * 2 + dir) * HID * BATCH;
  const int u0 = gb * 8 + quad;      // unit of acc[0]
  const int u1 = gb * 8 + 4 + quad;  // unit of acc[1]
  float c0 = 0.f, c1 = 0.f;
  if (t0 > 0) { c0 = cl[u0 * BATCH + b]; c1 = cl[u1 * BATCH + b]; }

  // Prefetched pre for the current step.
  float pf[2][4];
#pragma unroll
  for (int mi = 0; mi < 2; ++mi)
#pragma unroll
    for (int r = 0; r < 4; ++r) {
      int gp = gb * 32 + mi * 16 + quad * 4 + r;
      pf[mi][r] = pre[(((size_t)dir * CHK + 0) * G4 + gp) * BATCH + b];
    }

  for (int j = 0; j < CHK; ++j) {
    const int s = t0 + j;
    const int t = dir ? (TSEQ - 1 - s) : s;

    floatx4 acc[2];
#pragma unroll
    for (int mi = 0; mi < 2; ++mi)
#pragma unroll
      for (int r = 0; r < 4; ++r) acc[mi][r] = pf[mi][r];

    // Prefetch next step's pre early; independent of this step's h.
    if (j + 1 < CHK) {
#pragma unroll
      for (int mi = 0; mi < 2; ++mi)
#pragma unroll
        for (int r = 0; r < 4; ++r) {
          int gp = gb * 32 + mi * 16 + quad * 4 + r;
          pf[mi][r] = pre[(((size_t)dir * CHK + (j + 1)) * G4 + gp) * BATCH + b];
        }
    }

    if (s > 0) {
      const unsigned short* hprev;
      int hstride;
      if (layer == 0) {
        int tp = dir ? t + 1 : t - 1;
        hprev = act1bf + (size_t)tp * BATCH * DIN + dir * HID;
        hstride = DIN;
      } else {
        hprev = hT2 + (size_t)(((s - 1) & 1) * 2 + dir) * BATCH * HID;
        hstride = HID;
      }
      const unsigned short* hrow = hprev + (size_t)b * hstride;
#pragma unroll
      for (int kt = 0; kt < 16; ++kt) {
        short8 bfr = *reinterpret_cast<const short8*>(hrow + kt * 32 + quad * 8);
        acc[0] = mfma16(wfr[kt][0], bfr, acc[0]);
        acc[1] = mfma16(wfr[kt][1], bfr, acc[1]);
      }
    }

    // LSTM nonlinearity (rows permuted so acc[mi] = (i,f,g,o) of unit u).
    float si = sigm(acc[0][0]);
    float sf = sigm(acc[0][1]);
    float tg = tanh_f(acc[0][2]);
    float so = sigm(acc[0][3]);
    c0 = c0 * si + sf * tg;
    float h0 = tanh_f(c0) * so;

    si = sigm(acc[1][0]);
    sf = sigm(acc[1][1]);
    tg = tanh_f(acc[1][2]);
    so = sigm(acc[1][3]);
    c1 = c1 * si + sf * tg;
    float h1 = tanh_f(c1) * so;

    if (layer == 0) {
      unsigned short* arow = act1bf + ((size_t)t * BATCH + b) * DIN + dir * HID;
      arow[u0] = f2bf(h0);
      arow[u1] = f2bf(h1);
    } else {
      unsigned short* hrow2 = hT2 + ((size_t)((s & 1) * 2 + dir) * BATCH + b) * HID;
      hrow2[u0] = f2bf(h0);
      hrow2[u1] = f2bf(h1);
      float* drow = dout + ((size_t)t * BATCH + b) * DIN + dir * HID;
      drow[u0] = h0;
      drow[u1] = h1;
    }

    // Publish h to the sibling blocks of this direction; the last step needs no
    // barrier (the next launch is stream-ordered).
    if (j + 1 < CHK) {
      dir_barrier(ctr, bar_base + (unsigned)(j + 1) * 64);
    }
  }

  cl[u0 * BATCH + b] = c0;
  cl[u1 * BATCH + b] = c1;
}

extern "C" void kernel_launch(void* const* d_in, const int* in_sizes, int n_in,
                              void* d_out, int out_size, void* d_ws, size_t ws_size,
                              hipStream_t stream) {
  const float* x = (const float*)d_in[0];
  const float* W_ih = (const float*)d_in[1];
  const float* b_ih = (const float*)d_in[2];
  const float* W_hh = (const float*)d_in[3];
  const float* b_hh = (const float*)d_in[4];
  float* dout = (float*)d_out;

  char* p = (char*)d_ws;
  auto alloc = [&](size_t bytes) {
    char* r = p;
    p += (bytes + 255) & ~(size_t)255;
    return r;
  };
  unsigned short* xbf    = (unsigned short*)alloc((size_t)TSEQ * BATCH * DIN * 2);
  unsigned short* act1bf = (unsigned short*)alloc((size_t)TSEQ * BATCH * DIN * 2);
  float*          pre    = (float*)alloc((size_t)2 * CHK * G4 * BATCH * 4);
  unsigned short* Wihf   = (unsigned short*)alloc((size_t)4 * G4 * DIN * 2);
  unsigned short* Whhf   = (unsigned short*)alloc((size_t)4 * G4 * HID * 2);
  float*          biasf  = (float*)alloc((size_t)4 * G4 * 4);
  float*          cst    = (float*)alloc((size_t)4 * HID * BATCH * 4);
  unsigned short* hT2    = (unsigned short*)alloc((size_t)4 * BATCH * HID * 2);
  unsigned int*   bar    = (unsigned int*)alloc(512);

  size_t required = (size_t)(p - (char*)d_ws);
  if (ws_size < required) return;  // fail visibly rather than corrupt memory

  int n4 = TSEQ * BATCH * DIN / 4;
  k_zero_bar<<<dim3(1), dim3(64), 0, stream>>>(bar);
  k_convert_x<<<dim3((n4 + 255) / 256), dim3(256), 0, stream>>>(x, xbf, n4);
  k_prep_w<<<dim3(G4 / 16, DIN / 32, 4), dim3(64), 0, stream>>>(W_ih, Wihf, DIN);
  k_prep_w<<<dim3(G4 / 16, HID / 32, 4), dim3(64), 0, stream>>>(W_hh, Whhf, HID);
  k_prep_bias<<<dim3(32), dim3(256), 0, stream>>>(b_ih, b_hh, biasf);

  unsigned int bar_base = 0;
  for (int l = 0; l < 2; ++l) {
    const unsigned short* xin = l ? act1bf : xbf;
    const unsigned short* Wfl = Wihf + (size_t)l * 2 * G4 * DIN;
    const unsigned short* Whl = Whhf + (size_t)l * 2 * G4 * HID;
    const float* bfl = biasf + (size_t)l * 2 * G4;
    for (int c = 0; c < TSEQ / CHK; ++c) {
      k_proj<<<dim3(G4 / 128, CHK / 4, 2), dim3(256), 0, stream>>>(xin, Wfl, bfl, pre, c * CHK);
      k_steps<<<dim3(G4 / 32, 2), dim3(256), 0, stream>>>(Whl, pre, act1bf, hT2, cst, dout,
                                                          bar, c * CHK, l, bar_base);
      bar_base += (unsigned)(CHK - 1) * 64;
    }
  }
  (void)in_sizes; (void)n_in; (void)out_size;
}

// Round 2
// 7177.592 us; speedup vs baseline: 1.6909x; 1.6909x over previous
//
#include <hip/hip_runtime.h>

#define TSEQ 512
#define BATCH 64
#define DIN 1024
#define HID 512
#define G4 2048
#define CHK 64

typedef __attribute__((ext_vector_type(8))) short short8;
typedef __attribute__((ext_vector_type(4))) float floatx4;

__device__ __forceinline__ floatx4 mfma16(short8 a, short8 b, floatx4 c) {
  return __builtin_amdgcn_mfma_f32_16x16x32_bf16(a, b, c, 0, 0, 0);
}

__device__ __forceinline__ unsigned short f2bf(float f) {
  unsigned int u = __float_as_uint(f);
  unsigned int r = (u + 0x7fffu + ((u >> 16) & 1u)) >> 16;
  return (unsigned short)r;
}

__device__ __forceinline__ float sigm(float x) { return 1.f / (1.f + __expf(-x)); }
__device__ __forceinline__ float tanh_f(float x) {
  float xx = fminf(fmaxf(x, -15.f), 15.f);
  float e = __expf(2.f * xx);
  return (e - 1.f) / (e + 1.f);
}

// Agent-scope coherent (L3) access helpers: relaxed atomics compile to
// sc0|sc1-flagged loads/stores that bypass the non-coherent per-XCD L1/L2.
// No cache-maintenance fences (buffer_wbl2/buffer_inv) are ever issued.
__device__ __forceinline__ unsigned long long coh_load_q(const unsigned long long* p) {
  return __hip_atomic_load(p, __ATOMIC_RELAXED, __HIP_MEMORY_SCOPE_AGENT);
}
__device__ __forceinline__ void coh_store_u32(unsigned int* p, unsigned int v) {
  __hip_atomic_store(p, v, __ATOMIC_RELAXED, __HIP_MEMORY_SCOPE_AGENT);
}

// Convert fp32 x -> bf16 (same [T][B][DIN] layout, k-contiguous for B-fragments)
__global__ void k_convert_x(const float* __restrict__ x, unsigned short* __restrict__ xbf, int n4) {
  int i = blockIdx.x * 256 + threadIdx.x;
  if (i >= n4) return;
  floatx4 v = reinterpret_cast<const floatx4*>(x)[i];
  union { unsigned short us[4]; unsigned long long ull; } pk;
  pk.us[0] = f2bf(v[0]); pk.us[1] = f2bf(v[1]); pk.us[2] = f2bf(v[2]); pk.us[3] = f2bf(v[3]);
  reinterpret_cast<unsigned long long*>(xbf)[i] = pk.ull;
}

// Pre-arrange W [L][2][2048][K] fp32 into bf16 MFMA A-fragment order.
// Permuted row index rp = mt*16 + i encodes: gate = i&3,
// unit = (mt>>1)*8 + (i>>2)*2 + (mt&1)   (orig row = gate*512 + unit).
// This makes the two units a k_steps thread produces ADJACENT (u1 = u0+1),
// so h can be written as one packed 4B coherent store.
__global__ void k_prep_w(const float* __restrict__ W, unsigned short* __restrict__ Wf, int K) {
  int mt = blockIdx.x, kt = blockIdx.y, ld = blockIdx.z;
  int lane = threadIdx.x;
  int i = lane & 15;
  int unit = (mt >> 1) * 8 + (i >> 2) * 2 + (mt & 1);
  int row = (i & 3) * HID + unit;
  int k0 = kt * 32 + (lane >> 4) * 8;
  const float* src = W + (size_t)ld * G4 * K + (size_t)row * K + k0;
  unsigned short* dst = Wf + (size_t)ld * G4 * K + (((size_t)mt * (K / 32) + kt) * 64 + lane) * 8;
  for (int j = 0; j < 8; ++j) dst[j] = f2bf(src[j]);
}

// biasf[l][d][rp] = b_ih + b_hh at the permuted row (same mapping as k_prep_w).
__global__ void k_prep_bias(const float* __restrict__ bih, const float* __restrict__ bhh,
                            float* __restrict__ biasf) {
  int idx = blockIdx.x * 256 + threadIdx.x;  // 0 .. 4*2048-1
  int ld = idx >> 11;
  int rp = idx & 2047;
  int unit = (rp >> 5) * 8 + ((rp >> 2) & 3) * 2 + ((rp >> 4) & 1);
  int row = (rp & 3) * HID + unit;
  biasf[idx] = bih[ld * G4 + row] + bhh[ld * G4 + row];
}

// Zero the inter-block barrier counters (runs once per graph replay).
__global__ void k_zero_bar(unsigned int* bar) {
  if (threadIdx.x < 2) bar[threadIdx.x * 64] = 0;
}

// Input projection for one T-chunk (both directions).
__global__ __launch_bounds__(256, 2) void k_proj(
    const unsigned short* __restrict__ xin,   // [T][B][DIN] bf16
    const unsigned short* __restrict__ Wf,    // this layer: [2][G4*DIN] frag order
    const float* __restrict__ biasf,          // this layer: [2][G4] permuted
    float* __restrict__ pre,                  // [2][CHK][G4][B]
    int t0) {
  const int dir = blockIdx.z;
  const int w = threadIdx.x >> 6;
  const int lane = threadIdx.x & 63;
  const int quad = lane >> 4, col = lane & 15;
  const int tloc = blockIdx.y * 4 + w;
  const int tg = dir ? (TSEQ - 1 - (t0 + tloc)) : (t0 + tloc);
  const unsigned short* Wd = Wf + (size_t)dir * G4 * DIN;
  const unsigned short* xrow = xin + (size_t)tg * BATCH * DIN;

  floatx4 acc[8][4];
#pragma unroll
  for (int mi = 0; mi < 8; ++mi)
#pragma unroll
    for (int ni = 0; ni < 4; ++ni) acc[mi][ni] = (floatx4){0.f, 0.f, 0.f, 0.f};

#pragma unroll 4
  for (int kt = 0; kt < 32; ++kt) {
    short8 bfr[4];
#pragma unroll
    for (int ni = 0; ni < 4; ++ni) {
      int b = ni * 16 + col;
      bfr[ni] = *reinterpret_cast<const short8*>(xrow + (size_t)b * DIN + kt * 32 + quad * 8);
    }
#pragma unroll
    for (int mi = 0; mi < 8; ++mi) {
      size_t mt = (size_t)(blockIdx.x * 8 + mi);
      short8 afr = *reinterpret_cast<const short8*>(Wd + ((mt * 32 + kt) * 64 + lane) * 8);
#pragma unroll
      for (int ni = 0; ni < 4; ++ni) acc[mi][ni] = mfma16(afr, bfr[ni], acc[mi][ni]);
    }
  }

#pragma unroll
  for (int mi = 0; mi < 8; ++mi) {
    int gbase = blockIdx.x * 128 + mi * 16 + quad * 4;
#pragma unroll
    for (int r = 0; r < 4; ++r) {
      float bv = biasf[dir * G4 + gbase + r];
      float* prow = pre + (((size_t)dir * CHK + tloc) * G4 + gbase + r) * BATCH;
#pragma unroll
      for (int ni = 0; ni < 4; ++ni) prow[ni * 16 + col] = acc[mi][ni][r] + bv;
    }
  }
}

// Cheap device barrier across the 64 blocks of one direction.
// __syncthreads() already drains each wave's stores (vmcnt(0) before s_barrier),
// and all h traffic is L3-coherent (sc0|sc1), so NO cache-maintenance fence is
// needed — this was the 11.7us/step cost in the previous version.
__device__ __forceinline__ void dir_barrier(unsigned int* ctr, unsigned int target) {
  __syncthreads();
  if (threadIdx.x == 0) {
    __hip_atomic_fetch_add(ctr, 1u, __ATOMIC_RELAXED, __HIP_MEMORY_SCOPE_AGENT);
    while (__hip_atomic_load(ctr, __ATOMIC_RELAXED, __HIP_MEMORY_SCOPE_AGENT) < target) {
      __builtin_amdgcn_s_sleep(1);
    }
  }
  __syncthreads();
}

// Persistent recurrence kernel: runs CHK timesteps in ONE launch.
// Grid (64, 2) = 128 blocks <= 256 CUs -> all co-resident, spin-safe.
__global__ __launch_bounds__(256, 1) void k_steps(
    const unsigned short* __restrict__ Whhf,  // this layer: [2][G4*HID] frag order
    const float* __restrict__ pre,            // [2][CHK][G4][B]
    unsigned short* act1bf,                   // [T][B][DIN] bf16 (layer-1 h, layer-2 input)
    unsigned short* hT2,                      // [2 slots][2 dir][B][HID] bf16
    float* cst,                               // [2 layer][2 dir][HID][B] fp32
    float* __restrict__ dout,                 // [T][B][DIN] fp32
    unsigned int* bar,                        // [2 dirs] counters, 256B apart
    int t0, int layer, unsigned int bar_base) {
  const int dir = blockIdx.y;
  const int gb = blockIdx.x;
  const int w = threadIdx.x >> 6;
  const int lane = threadIdx.x & 63;
  const int quad = lane >> 4, col = lane & 15;
  const int b = w * 16 + col;
  unsigned int* ctr = bar + dir * 64;

  // Whh A-fragments for this block's 32 gate-rows: 32 x short8 = 128 VGPRs.
  // asm-pin each fragment so the compiler cannot rematerialize the loads
  // inside the step loop (round-1 disasm evidence: VGPR_Count=100 < 128).
  const unsigned short* Wd = Whhf + (size_t)dir * G4 * HID;
  short8 wfr[16][2];
#pragma unroll
  for (int kt = 0; kt < 16; ++kt)
#pragma unroll
    for (int mi = 0; mi < 2; ++mi) {
      size_t mt = (size_t)(gb * 2 + mi);
      wfr[kt][mi] = *reinterpret_cast<const short8*>(Wd + ((mt * 16 + kt) * 64 + lane) * 8);
    }
#pragma unroll
  for (int kt = 0; kt < 16; ++kt) {
    asm volatile("" : "+v"(wfr[kt][0]), "+v"(wfr[kt][1]));
  }

  // c-state in registers across the whole chunk. With the new permutation the
  // two units of this thread are adjacent: u0 even, u1 = u0+1.
  float* cl = cst + ((size_t)layer * 2 + dir) * HID * BATCH;
  const int u0 = gb * 8 + quad * 2;
  const int u1 = u0 + 1;
  float c0 = 0.f, c1 = 0.f;
  if (t0 > 0) { c0 = cl[u0 * BATCH + b]; c1 = cl[u1 * BATCH + b]; }

  // Prefetched pre for the current step (normal cached loads; pre is private
  // to this launch after the stream-ordered k_proj).
  float pf[2][4];
#pragma unroll
  for (int mi = 0; mi < 2; ++mi)
#pragma unroll
    for (int r = 0; r < 4; ++r) {
      int gp = gb * 32 + mi * 16 + quad * 4 + r;
      pf[mi][r] = pre[(((size_t)dir * CHK + 0) * G4 + gp) * BATCH + b];
    }

  for (int j = 0; j < CHK; ++j) {
    const int s = t0 + j;
    const int t = dir ? (TSEQ - 1 - s) : s;

    floatx4 acc[2];
#pragma unroll
    for (int mi = 0; mi < 2; ++mi)
#pragma unroll
      for (int r = 0; r < 4; ++r) acc[mi][r] = pf[mi][r];

    // Prefetch next step's pre early; independent of this step's h.
    if (j + 1 < CHK) {
#pragma unroll
      for (int mi = 0; mi < 2; ++mi)
#pragma unroll
        for (int r = 0; r < 4; ++r) {
          int gp = gb * 32 + mi * 16 + quad * 4 + r;
          pf[mi][r] = pre[(((size_t)dir * CHK + (j + 1)) * G4 + gp) * BATCH + b];
        }
    }

    if (s > 0) {
      const unsigned short* hprev;
      int hstride;
      if (layer == 0) {
        int tp = dir ? t + 1 : t - 1;
        hprev = act1bf + (size_t)tp * BATCH * DIN + dir * HID;
        hstride = DIN;
      } else {
        hprev = hT2 + (size_t)(((s - 1) & 1) * 2 + dir) * BATCH * HID;
        hstride = HID;
      }
      // Stage the full h row (1KB) with L3-coherent loads FIRST (issued
      // back-to-back, one waitcnt), then run the MFMA chain.
      const unsigned long long* hq =
          reinterpret_cast<const unsigned long long*>(hprev + (size_t)b * hstride);
      short8 hb[16];
#pragma unroll
      for (int kt = 0; kt < 16; ++kt) {
        union { unsigned long long q[2]; short8 v; } u;
        u.q[0] = coh_load_q(hq + kt * 8 + quad * 2);
        u.q[1] = coh_load_q(hq + kt * 8 + quad * 2 + 1);
        hb[kt] = u.v;
      }
#pragma unroll
      for (int kt = 0; kt < 16; ++kt) {
        acc[0] = mfma16(wfr[kt][0], hb[kt], acc[0]);
        acc[1] = mfma16(wfr[kt][1], hb[kt], acc[1]);
      }
    }

    // LSTM nonlinearity (rows permuted so acc[mi][r] = gate r of unit u).
    float si = sigm(acc[0][0]);
    float sf = sigm(acc[0][1]);
    float tg = tanh_f(acc[0][2]);
    float so = sigm(acc[0][3]);
    c0 = c0 * si + sf * tg;
    float h0 = tanh_f(c0) * so;

    si = sigm(acc[1][0]);
    sf = sigm(acc[1][1]);
    tg = tanh_f(acc[1][2]);
    so = sigm(acc[1][3]);
    c1 = c1 * si + sf * tg;
    float h1 = tanh_f(c1) * so;

    unsigned int hp = (unsigned int)f2bf(h0) | ((unsigned int)f2bf(h1) << 16);
    if (layer == 0) {
      unsigned short* arow = act1bf + ((size_t)t * BATCH + b) * DIN + dir * HID;
      coh_store_u32(reinterpret_cast<unsigned int*>(arow + u0), hp);
    } else {
      unsigned short* hrow2 = hT2 + ((size_t)((s & 1) * 2 + dir) * BATCH + b) * HID;
      coh_store_u32(reinterpret_cast<unsigned int*>(hrow2 + u0), hp);
      float* drow = dout + ((size_t)t * BATCH + b) * DIN + dir * HID;
      *reinterpret_cast<float2*>(drow + u0) = make_float2(h0, h1);
    }

    // Publish h to the sibling blocks of this direction; the last step needs
    // no barrier (the next launch is stream-ordered).
    if (j + 1 < CHK) {
      dir_barrier(ctr, bar_base + (unsigned)(j + 1) * 64);
    }
  }

  cl[u0 * BATCH + b] = c0;
  cl[u1 * BATCH + b] = c1;
}

extern "C" void kernel_launch(void* const* d_in, const int* in_sizes, int n_in,
                              void* d_out, int out_size, void* d_ws, size_t ws_size,
                              hipStream_t stream) {
  const float* x = (const float*)d_in[0];
  const float* W_ih = (const float*)d_in[1];
  const float* b_ih = (const float*)d_in[2];
  const float* W_hh = (const float*)d_in[3];
  const float* b_hh = (const float*)d_in[4];
  float* dout = (float*)d_out;

  char* p = (char*)d_ws;
  auto alloc = [&](size_t bytes) {
    char* r = p;
    p += (bytes + 255) & ~(size_t)255;
    return r;
  };
  unsigned short* xbf    = (unsigned short*)alloc((size_t)TSEQ * BATCH * DIN * 2);
  unsigned short* act1bf = (unsigned short*)alloc((size_t)TSEQ * BATCH * DIN * 2);
  float*          pre    = (float*)alloc((size_t)2 * CHK * G4 * BATCH * 4);
  unsigned short* Wihf   = (unsigned short*)alloc((size_t)4 * G4 * DIN * 2);
  unsigned short* Whhf   = (unsigned short*)alloc((size_t)4 * G4 * HID * 2);
  float*          biasf  = (float*)alloc((size_t)4 * G4 * 4);
  float*          cst    = (float*)alloc((size_t)4 * HID * BATCH * 4);
  unsigned short* hT2    = (unsigned short*)alloc((size_t)4 * BATCH * HID * 2);
  unsigned int*   bar    = (unsigned int*)alloc(512);

  size_t required = (size_t)(p - (char*)d_ws);
  if (ws_size < required) return;  // fail visibly rather than corrupt memory

  int n4 = TSEQ * BATCH * DIN / 4;
  k_zero_bar<<<dim3(1), dim3(64), 0, stream>>>(bar);
  k_convert_x<<<dim3((n4 + 255) / 256), dim3(256), 0, stream>>>(x, xbf, n4);
  k_prep_w<<<dim3(G4 / 16, DIN / 32, 4), dim3(64), 0, stream>>>(W_ih, Wihf, DIN);
  k_prep_w<<<dim3(G4 / 16, HID / 32, 4), dim3(64), 0, stream>>>(W_hh, Whhf, HID);
  k_prep_bias<<<dim3(32), dim3(256), 0, stream>>>(b_ih, b_hh, biasf);

  unsigned int bar_base = 0;
  for (int l = 0; l < 2; ++l) {
    const unsigned short* xin = l ? act1bf : xbf;
    const unsigned short* Wfl = Wihf + (size_t)l * 2 * G4 * DIN;
    const unsigned short* Whl = Whhf + (size_t)l * 2 * G4 * HID;
    const float* bfl = biasf + (size_t)l * 2 * G4;
    for (int c = 0; c < TSEQ / CHK; ++c) {
      k_proj<<<dim3(G4 / 128, CHK / 4, 2), dim3(256), 0, stream>>>(xin, Wfl, bfl, pre, c * CHK);
      k_steps<<<dim3(G4 / 32, 2), dim3(256), 0, stream>>>(Whl, pre, act1bf, hT2, cst, dout,
                                                          bar, c * CHK, l, bar_base);
      bar_base += (unsigned)(CHK - 1) * 64;
    }
  }
  (void)in_sizes; (void)n_in; (void)out_size;
}

// Round 3
// 6489.513 us; speedup vs baseline: 1.8701x; 1.1060x over previous
//
#include <hip/hip_runtime.h>

#define TSEQ 512
#define BATCH 64
#define DIN 1024
#define HID 512
#define G4 2048
#define CHK 64

typedef __attribute__((ext_vector_type(8))) short short8;
typedef __attribute__((ext_vector_type(4))) float floatx4;

__device__ __forceinline__ floatx4 mfma16(short8 a, short8 b, floatx4 c) {
  return __builtin_amdgcn_mfma_f32_16x16x32_bf16(a, b, c, 0, 0, 0);
}

__device__ __forceinline__ unsigned short f2bf(float f) {
  unsigned int u = __float_as_uint(f);
  unsigned int r = (u + 0x7fffu + ((u >> 16) & 1u)) >> 16;
  return (unsigned short)r;
}

__device__ __forceinline__ float sigm(float x) { return 1.f / (1.f + __expf(-x)); }
__device__ __forceinline__ float tanh_f(float x) {
  float xx = fminf(fmaxf(x, -15.f), 15.f);
  float e = __expf(2.f * xx);
  return (e - 1.f) / (e + 1.f);
}

// Agent-scope coherent (L3) access helpers: relaxed atomics compile to
// sc0|sc1-flagged loads/stores that bypass the non-coherent per-XCD L1/L2.
// No cache-maintenance fences are ever issued (round-1 lesson: a
// __threadfence L2 writeback+inv per step cost ~10us/step).
__device__ __forceinline__ unsigned long long coh_load_q(const unsigned long long* p) {
  return __hip_atomic_load(p, __ATOMIC_RELAXED, __HIP_MEMORY_SCOPE_AGENT);
}
__device__ __forceinline__ unsigned int coh_load_u32(const unsigned int* p) {
  return __hip_atomic_load(p, __ATOMIC_RELAXED, __HIP_MEMORY_SCOPE_AGENT);
}
__device__ __forceinline__ void coh_store_u32(unsigned int* p, unsigned int v) {
  __hip_atomic_store(p, v, __ATOMIC_RELAXED, __HIP_MEMORY_SCOPE_AGENT);
}

// Convert fp32 x -> bf16 (same [T][B][DIN] layout, k-contiguous for B-fragments)
__global__ void k_convert_x(const float* __restrict__ x, unsigned short* __restrict__ xbf, int n4) {
  int i = blockIdx.x * 256 + threadIdx.x;
  if (i >= n4) return;
  floatx4 v = reinterpret_cast<const floatx4*>(x)[i];
  union { unsigned short us[4]; unsigned long long ull; } pk;
  pk.us[0] = f2bf(v[0]); pk.us[1] = f2bf(v[1]); pk.us[2] = f2bf(v[2]); pk.us[3] = f2bf(v[3]);
  reinterpret_cast<unsigned long long*>(xbf)[i] = pk.ull;
}

// Pre-arrange W [L][2][2048][K] fp32 into bf16 MFMA A-fragment order.
// Permuted row index rp = mt*16 + i encodes: gate = i&3,
// unit = (mt>>1)*8 + (i>>2)*2 + (mt&1)   (orig row = gate*512 + unit).
// The two units a k_steps thread produces are ADJACENT (u1 = u0+1),
// so h is written as one packed 4B coherent store.
__global__ void k_prep_w(const float* __restrict__ W, unsigned short* __restrict__ Wf, int K) {
  int mt = blockIdx.x, kt = blockIdx.y, ld = blockIdx.z;
  int lane = threadIdx.x;
  int i = lane & 15;
  int unit = (mt >> 1) * 8 + (i >> 2) * 2 + (mt & 1);
  int row = (i & 3) * HID + unit;
  int k0 = kt * 32 + (lane >> 4) * 8;
  const float* src = W + (size_t)ld * G4 * K + (size_t)row * K + k0;
  unsigned short* dst = Wf + (size_t)ld * G4 * K + (((size_t)mt * (K / 32) + kt) * 64 + lane) * 8;
  for (int j = 0; j < 8; ++j) dst[j] = f2bf(src[j]);
}

// biasf[l][d][rp] = b_ih + b_hh at the permuted row (same mapping as k_prep_w).
__global__ void k_prep_bias(const float* __restrict__ bih, const float* __restrict__ bhh,
                            float* __restrict__ biasf) {
  int idx = blockIdx.x * 256 + threadIdx.x;  // 0 .. 4*2048-1
  int ld = idx >> 11;
  int rp = idx & 2047;
  int unit = (rp >> 5) * 8 + ((rp >> 2) & 3) * 2 + ((rp >> 4) & 1);
  int row = (rp & 3) * HID + unit;
  biasf[idx] = bih[ld * G4 + row] + bhh[ld * G4 + row];
}

// Zero the 2x64 flag slots (64B apart). Runs once per graph replay.
__global__ void k_zero_bar(unsigned int* bar) {
  int i = threadIdx.x;
  if (i < 128) bar[i * 16] = 0;
}

// Input projection for one T-chunk (both directions).
__global__ __launch_bounds__(256, 2) void k_proj(
    const unsigned short* __restrict__ xin,   // [T][B][DIN] bf16
    const unsigned short* __restrict__ Wf,    // this layer: [2][G4*DIN] frag order
    const float* __restrict__ biasf,          // this layer: [2][G4] permuted
    float* __restrict__ pre,                  // [2][CHK][G4][B]
    int t0) {
  const int dir = blockIdx.z;
  const int w = threadIdx.x >> 6;
  const int lane = threadIdx.x & 63;
  const int quad = lane >> 4, col = lane & 15;
  const int tloc = blockIdx.y * 4 + w;
  const int tg = dir ? (TSEQ - 1 - (t0 + tloc)) : (t0 + tloc);
  const unsigned short* Wd = Wf + (size_t)dir * G4 * DIN;
  const unsigned short* xrow = xin + (size_t)tg * BATCH * DIN;

  floatx4 acc[8][4];
#pragma unroll
  for (int mi = 0; mi < 8; ++mi)
#pragma unroll
    for (int ni = 0; ni < 4; ++ni) acc[mi][ni] = (floatx4){0.f, 0.f, 0.f, 0.f};

#pragma unroll 4
  for (int kt = 0; kt < 32; ++kt) {
    short8 bfr[4];
#pragma unroll
    for (int ni = 0; ni < 4; ++ni) {
      int b = ni * 16 + col;
      bfr[ni] = *reinterpret_cast<const short8*>(xrow + (size_t)b * DIN + kt * 32 + quad * 8);
    }
#pragma unroll
    for (int mi = 0; mi < 8; ++mi) {
      size_t mt = (size_t)(blockIdx.x * 8 + mi);
      short8 afr = *reinterpret_cast<const short8*>(Wd + ((mt * 32 + kt) * 64 + lane) * 8);
#pragma unroll
      for (int ni = 0; ni < 4; ++ni) acc[mi][ni] = mfma16(afr, bfr[ni], acc[mi][ni]);
    }
  }

#pragma unroll
  for (int mi = 0; mi < 8; ++mi) {
    int gbase = blockIdx.x * 128 + mi * 16 + quad * 4;
#pragma unroll
    for (int r = 0; r < 4; ++r) {
      float bv = biasf[dir * G4 + gbase + r];
      float* prow = pre + (((size_t)dir * CHK + tloc) * G4 + gbase + r) * BATCH;
#pragma unroll
      for (int ni = 0; ni < 4; ++ni) prow[ni * 16 + col] = acc[mi][ni][r] + bv;
    }
  }
}

// Distributed flag wait: lane i watches block i's flag (64B apart -> no line
// contention). All waves of the block spin independently; plain relaxed
// coherent loads, no atomics, no RMW serialization at the coherence point.
__device__ __forceinline__ void wait_flags(const unsigned int* flags, unsigned int target) {
  const int lane = threadIdx.x & 63;
  const unsigned int* p = flags + lane * 16;
  while (true) {
    unsigned int v = coh_load_u32(p);
    if (__all((int)(v >= target))) break;
    __builtin_amdgcn_s_sleep(1);
  }
}

// Persistent recurrence kernel: runs CHK timesteps in ONE launch.
// Grid (64, 2) = 128 blocks <= 256 CUs -> all co-resident, spin-safe.
// Whh slice (32 rows = 32KB, contiguous in fragment order) lives in LDS.
__global__ __launch_bounds__(256, 1) void k_steps(
    const unsigned short* __restrict__ Whhf,  // this layer: [2][G4*HID] frag order
    const float* __restrict__ pre,            // [2][CHK][G4][B]
    unsigned short* act1bf,                   // [T][B][DIN] bf16 (layer-1 h, layer-2 input)
    unsigned short* hT2,                      // [2 slots][2 dir][B][HID] bf16
    float* cst,                               // [2 layer][2 dir][HID][B] fp32
    float* __restrict__ dout,                 // [T][B][DIN] fp32
    unsigned int* bar,                        // [2 dirs][64 blocks] flags, 64B stride
    int t0, int layer, unsigned int bar_base) {
  const int dir = blockIdx.y;
  const int gb = blockIdx.x;
  const int w = threadIdx.x >> 6;
  const int lane = threadIdx.x & 63;
  const int quad = lane >> 4, col = lane & 15;
  const int b = w * 16 + col;
  unsigned int* flags = bar + dir * 1024;  // 64 flags * 16-uint stride

  // Stage this block's Whh slice (rows gb*32..gb*32+31 in fragment order,
  // one contiguous 32KB region) into LDS.
  __shared__ unsigned short wlds[32 * HID];  // 32KB
  {
    const uint4* src = reinterpret_cast<const uint4*>(
        Whhf + (size_t)dir * G4 * HID + (size_t)gb * 16384);
    uint4* dst = reinterpret_cast<uint4*>(wlds);
#pragma unroll
    for (int it = 0; it < 8; ++it) dst[it * 256 + threadIdx.x] = src[it * 256 + threadIdx.x];
  }

  // c-state in registers across the whole chunk. Two adjacent units per thread.
  float* cl = cst + ((size_t)layer * 2 + dir) * HID * BATCH;
  const int u0 = gb * 8 + quad * 2;
  const int u1 = u0 + 1;
  float c0 = 0.f, c1 = 0.f;
  if (t0 > 0) { c0 = cl[u0 * BATCH + b]; c1 = cl[u1 * BATCH + b]; }

  // Prefetched pre for the current step (plain cached loads; pre was produced
  // by the stream-ordered k_proj, so kernel-boundary coherence applies).
  float pf[2][4];
#pragma unroll
  for (int mi = 0; mi < 2; ++mi)
#pragma unroll
    for (int r = 0; r < 4; ++r) {
      int gp = gb * 32 + mi * 16 + quad * 4 + r;
      pf[mi][r] = pre[(((size_t)dir * CHK + 0) * G4 + gp) * BATCH + b];
    }

  __syncthreads();  // wlds ready

  for (int j = 0; j < CHK; ++j) {
    const int s = t0 + j;
    const int t = dir ? (TSEQ - 1 - s) : s;

    floatx4 acc[2];
#pragma unroll
    for (int mi = 0; mi < 2; ++mi)
#pragma unroll
      for (int r = 0; r < 4; ++r) acc[mi][r] = pf[mi][r];

    // Prefetch next step's pre early (independent of h) so its L3/HBM latency
    // overlaps the flag spin.
    if (j + 1 < CHK) {
#pragma unroll
      for (int mi = 0; mi < 2; ++mi)
#pragma unroll
        for (int r = 0; r < 4; ++r) {
          int gp = gb * 32 + mi * 16 + quad * 4 + r;
          pf[mi][r] = pre[(((size_t)dir * CHK + (j + 1)) * G4 + gp) * BATCH + b];
        }
    }

    if (s > 0) {
      if (j >= 1) wait_flags(flags, bar_base + (unsigned)j);

      const unsigned short* hprev;
      int hstride;
      if (layer == 0) {
        int tp = dir ? t + 1 : t - 1;
        hprev = act1bf + (size_t)tp * BATCH * DIN + dir * HID;
        hstride = DIN;
      } else {
        hprev = hT2 + (size_t)(((s - 1) & 1) * 2 + dir) * BATCH * HID;
        hstride = HID;
      }
      // Stage the full h row (1KB) with L3-coherent loads (issued
      // back-to-back), then run the LDS-fed MFMA chain.
      const unsigned long long* hq =
          reinterpret_cast<const unsigned long long*>(hprev + (size_t)b * hstride);
      short8 hb[16];
#pragma unroll
      for (int kt = 0; kt < 16; ++kt) {
        union { unsigned long long q[2]; short8 v; } u;
        u.q[0] = coh_load_q(hq + kt * 8 + quad * 2);
        u.q[1] = coh_load_q(hq + kt * 8 + quad * 2 + 1);
        hb[kt] = u.v;
      }
#pragma unroll
      for (int kt = 0; kt < 16; ++kt) {
        short8 w0 = *reinterpret_cast<const short8*>(wlds + ((0 * 16 + kt) * 64 + lane) * 8);
        short8 w1 = *reinterpret_cast<const short8*>(wlds + ((1 * 16 + kt) * 64 + lane) * 8);
        acc[0] = mfma16(w0, hb[kt], acc[0]);
        acc[1] = mfma16(w1, hb[kt], acc[1]);
      }
    }

    // LSTM nonlinearity (rows permuted so acc[mi][r] = gate r of unit u).
    float si = sigm(acc[0][0]);
    float sf = sigm(acc[0][1]);
    float tg = tanh_f(acc[0][2]);
    float so = sigm(acc[0][3]);
    c0 = c0 * si + sf * tg;
    float h0 = tanh_f(c0) * so;

    si = sigm(acc[1][0]);
    sf = sigm(acc[1][1]);
    tg = tanh_f(acc[1][2]);
    so = sigm(acc[1][3]);
    c1 = c1 * si + sf * tg;
    float h1 = tanh_f(c1) * so;

    unsigned int hp = (unsigned int)f2bf(h0) | ((unsigned int)f2bf(h1) << 16);
    if (layer == 0) {
      unsigned short* arow = act1bf + ((size_t)t * BATCH + b) * DIN + dir * HID;
      coh_store_u32(reinterpret_cast<unsigned int*>(arow + u0), hp);
    } else {
      unsigned short* hrow2 = hT2 + ((size_t)((s & 1) * 2 + dir) * BATCH + b) * HID;
      coh_store_u32(reinterpret_cast<unsigned int*>(hrow2 + u0), hp);
      float* drow = dout + ((size_t)t * BATCH + b) * DIN + dir * HID;
      *reinterpret_cast<float2*>(drow + u0) = make_float2(h0, h1);
    }

    // Publish: __syncthreads drains all waves' h stores (vmcnt 0 before
    // s_barrier), then thread 0 stores the monotone round id to OUR flag slot.
    // Plain store to a private 64B line -> no contention, no RMW.
    if (j + 1 < CHK) {
      __syncthreads();
      if (threadIdx.x == 0) coh_store_u32(flags + gb * 16, bar_base + (unsigned)(j + 1));
    }
  }

  cl[u0 * BATCH + b] = c0;
  cl[u1 * BATCH + b] = c1;
}

extern "C" void kernel_launch(void* const* d_in, const int* in_sizes, int n_in,
                              void* d_out, int out_size, void* d_ws, size_t ws_size,
                              hipStream_t stream) {
  const float* x = (const float*)d_in[0];
  const float* W_ih = (const float*)d_in[1];
  const float* b_ih = (const float*)d_in[2];
  const float* W_hh = (const float*)d_in[3];
  const float* b_hh = (const float*)d_in[4];
  float* dout = (float*)d_out;

  char* p = (char*)d_ws;
  auto alloc = [&](size_t bytes) {
    char* r = p;
    p += (bytes + 255) & ~(size_t)255;
    return r;
  };
  unsigned short* xbf    = (unsigned short*)alloc((size_t)TSEQ * BATCH * DIN * 2);
  unsigned short* act1bf = (unsigned short*)alloc((size_t)TSEQ * BATCH * DIN * 2);
  float*          pre    = (float*)alloc((size_t)2 * CHK * G4 * BATCH * 4);
  unsigned short* Wihf   = (unsigned short*)alloc((size_t)4 * G4 * DIN * 2);
  unsigned short* Whhf   = (unsigned short*)alloc((size_t)4 * G4 * HID * 2);
  float*          biasf  = (float*)alloc((size_t)4 * G4 * 4);
  float*          cst    = (float*)alloc((size_t)4 * HID * BATCH * 4);
  unsigned short* hT2    = (unsigned short*)alloc((size_t)4 * BATCH * HID * 2);
  unsigned int*   bar    = (unsigned int*)alloc((size_t)2 * 64 * 16 * 4);

  size_t required = (size_t)(p - (char*)d_ws);
  if (ws_size < required) return;  // fail visibly rather than corrupt memory

  int n4 = TSEQ * BATCH * DIN / 4;
  k_zero_bar<<<dim3(1), dim3(128), 0, stream>>>(bar);
  k_convert_x<<<dim3((n4 + 255) / 256), dim3(256), 0, stream>>>(x, xbf, n4);
  k_prep_w<<<dim3(G4 / 16, DIN / 32, 4), dim3(64), 0, stream>>>(W_ih, Wihf, DIN);
  k_prep_w<<<dim3(G4 / 16, HID / 32, 4), dim3(64), 0, stream>>>(W_hh, Whhf, HID);
  k_prep_bias<<<dim3(32), dim3(256), 0, stream>>>(b_ih, b_hh, biasf);

  unsigned int bar_base = 0;
  for (int l = 0; l < 2; ++l) {
    const unsigned short* xin = l ? act1bf : xbf;
    const unsigned short* Wfl = Wihf + (size_t)l * 2 * G4 * DIN;
    const unsigned short* Whl = Whhf + (size_t)l * 2 * G4 * HID;
    const float* bfl = biasf + (size_t)l * 2 * G4;
    for (int c = 0; c < TSEQ / CHK; ++c) {
      k_proj<<<dim3(G4 / 128, CHK / 4, 2), dim3(256), 0, stream>>>(xin, Wfl, bfl, pre, c * CHK);
      k_steps<<<dim3(G4 / 32, 2), dim3(256), 0, stream>>>(Whl, pre, act1bf, hT2, cst, dout,
                                                          bar, c * CHK, l, bar_base);
      bar_base += (unsigned)(CHK - 1);
    }
  }
  (void)in_sizes; (void)n_in; (void)out_size;
}